// Round 23
// baseline (661.669 us; speedup 1.0000x reference)
//
#include <hip/hip_runtime.h>
#include <hip/hip_bf16.h>
#include <math.h>

#define EPSV 1e-10f
#define BNEPS 1e-5f
#define INV_SQRT2 0.70710678118654752440f

typedef __attribute__((ext_vector_type(8))) short short8;
typedef __attribute__((ext_vector_type(4))) float f32x4;
typedef _Float16 half8 __attribute__((ext_vector_type(8)));

__device__ __forceinline__ unsigned short f2h(float f) {
    _Float16 h = (_Float16)f;                      // RNE
    return __builtin_bit_cast(unsigned short, h);
}
__device__ __forceinline__ float h2f(unsigned short u) {
    _Float16 h = __builtin_bit_cast(_Float16, u);
    return (float)h;
}

// ---------------------------------------------------------------------------
// Fused prep: 5x prep_pack + packL1 + 4x prep_s in ONE kernel (disjoint outputs)
// ---------------------------------------------------------------------------
__device__ __forceinline__ void pack_one(const float* __restrict__ a,
        const float* __restrict__ b, unsigned short* __restrict__ pk,
        int Ci, int Co, int ver2, int idx, int total) {
    if (idx >= total) return;
    int lane = idx & 63;
    int MFg = Co >> 4, NCH = Ci >> 5;
    int mfch = idx >> 6;
    int mf = mfch % MFg;
    int chpos = mfch / MFg;
    int ch = chpos % NCH;
    int pos = chpos / NCH;
    int co = mf * 16 + (lane & 15);
    int cib = ch * 32 + (lane >> 4) * 8;
    unsigned int wa[4], wb[4];
#pragma unroll
    for (int j = 0; j < 8; j++) {
        long s = ((long)co * Ci + cib + j) * 9 + pos;
        float p0 = 1.f / (1.f + expf(-a[s]));
        float sb = 1.f / (1.f + expf(-b[s]));
        float p1 = (1.f - p0) * sb;
        float ew = 2.f * p1 - (1.f - p0);
        float ew2 = 1.f - p0;
        unsigned int ha = f2h(ew);
        unsigned int hb = f2h(ver2 ? ew * ew : ew2 - ew * ew);
        if (j & 1) { wa[j >> 1] |= ha << 16; wb[j >> 1] |= hb << 16; }
        else       { wa[j >> 1] = ha;        wb[j >> 1] = hb; }
    }
    long b0 = (((long)(0 * 9 + pos) * NCH + ch) * MFg + mf) * 64 + lane;
    long b1 = (((long)(1 * 9 + pos) * NCH + ch) * MFg + mf) * 64 + lane;
    uint4 va; va.x = wa[0]; va.y = wa[1]; va.z = wa[2]; va.w = wa[3];
    uint4 vb; vb.x = wb[0]; vb.y = wb[1]; vb.z = wb[2]; vb.w = wb[3];
    *(uint4*)(pk + b0 * 8) = va;
    *(uint4*)(pk + b1 * 8) = vb;
}

__device__ __forceinline__ void s_one(const float* __restrict__ alpha,
        float* __restrict__ s, int Ci, int co, int lane) {
    float acc[9];
#pragma unroll
    for (int k = 0; k < 9; k++) acc[k] = 0.f;
    for (int ci = lane; ci < Ci; ci += 64) {
        const float* p = alpha + ((long)co * Ci + ci) * 9;
#pragma unroll
        for (int k = 0; k < 9; k++) acc[k] += 1.f / (1.f + expf(p[k]));
    }
#pragma unroll
    for (int k = 0; k < 9; k++) {
        for (int off = 32; off > 0; off >>= 1) acc[k] += __shfl_down(acc[k], off);
    }
    if (lane == 0) {
#pragma unroll
        for (int k = 0; k < 9; k++) s[co * 9 + k] = acc[k];
    }
}

// grid 2588 x 256
__global__ void prep_all(
    const float* __restrict__ a1, const float* __restrict__ b1, unsigned short* __restrict__ pkL1,
    const float* __restrict__ a2, const float* __restrict__ b2, unsigned short* __restrict__ pk2,
    const float* __restrict__ a3, const float* __restrict__ b3, unsigned short* __restrict__ pk3,
    const float* __restrict__ a4, const float* __restrict__ b4, unsigned short* __restrict__ pk4,
    const float* __restrict__ a5, const float* __restrict__ b5, unsigned short* __restrict__ pk5,
    const float* __restrict__ a6, const float* __restrict__ b6, unsigned short* __restrict__ pk6,
    float* __restrict__ ss2, float* __restrict__ ss3,
    float* __restrict__ ss5, float* __restrict__ ss6)
{
    int bid = blockIdx.x;
    int tid = threadIdx.x;
    if (bid < 72) {
        pack_one(a2, b2, pk2, 128, 128, 1, bid * 256 + tid, 18432);
    } else if (bid < 216) {
        pack_one(a3, b3, pk3, 128, 256, 1, (bid - 72) * 256 + tid, 36864);
    } else if (bid < 504) {
        pack_one(a4, b4, pk4, 256, 256, 0, (bid - 216) * 256 + tid, 73728);
    } else if (bid < 1080) {
        pack_one(a5, b5, pk5, 256, 512, 1, (bid - 504) * 256 + tid, 147456);
    } else if (bid < 2232) {
        pack_one(a6, b6, pk6, 512, 512, 1, (bid - 1080) * 256 + tid, 294912);
    } else if (bid < 2236) {
        // packL1: prep_w math inlined (L1 is lrconv: WB = var_w)
        int idx = (bid - 2232) * 256 + tid;   // 1024 total
        if (idx >= 1024) return;
        int lane = idx & 63;
        int mf = (idx >> 6) & 7;
        int cv = idx >> 9;
        int co = mf * 16 + (lane & 15);
        int k0 = (lane >> 4) * 8;
        unsigned int o[4] = {0, 0, 0, 0};
#pragma unroll
        for (int j = 0; j < 8; j++) {
            int k = k0 + j;
            if (k < 27) {
                long sgi = (long)co * 27 + k;
                float p0 = 1.f / (1.f + expf(-a1[sgi]));
                float sb = 1.f / (1.f + expf(-b1[sgi]));
                float p1 = (1.f - p0) * sb;
                float ew = 2.f * p1 - (1.f - p0);
                float ew2 = 1.f - p0;
                float val = cv ? (ew2 - ew * ew) : ew;
                unsigned int h = f2h(val);
                o[j >> 1] |= h << ((j & 1) * 16);
            }
        }
        uint4 v; v.x = o[0]; v.y = o[1]; v.z = o[2]; v.w = o[3];
        *(uint4*)(pkL1 + (long)idx * 8) = v;
    } else {
        // prep_s: 4 co per block (64-lane groups); 1408 co total -> 352 blocks
        int cog = (bid - 2236) * 4 + (tid >> 6);
        int lane = tid & 63;
        if (cog < 128)       s_one(a2, ss2, 128, cog, lane);
        else if (cog < 384)  s_one(a3, ss3, 128, cog - 128, lane);
        else if (cog < 896)  s_one(a5, ss5, 256, cog - 384, lane);
        else if (cog < 1408) s_one(a6, ss6, 512, cog - 896, lane);
    }
}

// grid 544 x 256: all 4 ones-grids
__device__ __forceinline__ void ones_one(const float* __restrict__ ssum, float* __restrict__ og,
        int Hout, int Wout, int Hin, int Win, int stride, int idx) {
    int x = idx % Wout, y = (idx / Wout) % Hout, co = idx / (Wout * Hout);
    float s = 0.f;
    for (int ky = 0; ky < 3; ky++) {
        int yi = stride * y - 1 + ky;
        if (yi < 0 || yi >= Hin) continue;
        for (int kx = 0; kx < 3; kx++) {
            int xi = stride * x - 1 + kx;
            if (xi < 0 || xi >= Win) continue;
            s += ssum[co * 9 + ky * 3 + kx];
        }
    }
    og[idx] = s;
}

__global__ void prep_ones_all(const float* __restrict__ ss2, const float* __restrict__ ss3,
                              const float* __restrict__ ss5, const float* __restrict__ ss6,
                              float* __restrict__ og2, float* __restrict__ og3,
                              float* __restrict__ og5, float* __restrict__ og6) {
    int idx = blockIdx.x * 256 + threadIdx.x;     // 139264 total
    if (idx < 32768)        ones_one(ss2, og2, 16, 16, 32, 32, 2, idx);
    else if (idx < 98304)   ones_one(ss3, og3, 16, 16, 16, 16, 1, idx - 32768);
    else if (idx < 131072)  ones_one(ss5, og5, 8, 8, 8, 8, 1, idx - 98304);
    else if (idx < 139264)  ones_one(ss6, og6, 4, 4, 8, 8, 2, idx - 131072);
}

// ---------------------------------------------------------------------------
// FC1 weight pack: fp32 [1024][8192] -> fp16 A-fragment order
// ---------------------------------------------------------------------------
__global__ void prep_fc1(const float* __restrict__ W, unsigned short* __restrict__ pk) {
    int idx = blockIdx.x * 256 + threadIdx.x;
    int lane = idx & 63;
    int mf = (idx >> 6) & 63;
    int kt = idx >> 12;
    int o = mf * 16 + (lane & 15);
    long k = (long)kt * 32 + (lane >> 4) * 8;
    const float* src = W + (long)o * 8192 + k;
    float4 f0 = *(const float4*)src;
    float4 f1 = *(const float4*)(src + 4);
    uint4 v;
    v.x = (unsigned)f2h(f0.x) | ((unsigned)f2h(f0.y) << 16);
    v.y = (unsigned)f2h(f0.z) | ((unsigned)f2h(f0.w) << 16);
    v.z = (unsigned)f2h(f1.x) | ((unsigned)f2h(f1.y) << 16);
    v.w = (unsigned)f2h(f1.z) | ((unsigned)f2h(f1.w) << 16);
    *(uint4*)(pk + (long)idx * 8) = v;
}

// ---------------------------------------------------------------------------
// L1 MFMA GEMM with fused im2col (gathers window directly from fp32 x)
// ---------------------------------------------------------------------------
__global__ __launch_bounds__(512) void conv1_mfma(const float* __restrict__ x,
        const unsigned short* __restrict__ Wp, const float* __restrict__ bias,
        unsigned short* __restrict__ out) {
    constexpr int LINE = 80;
    constexpr int TSTR = 136;
    __shared__ char lds[128 * TSTR * 2];
    const int tid = threadIdx.x, lane = tid & 63, wv = tid >> 6;
    const int wm = wv & 1, wn = wv >> 1;
    const int g = lane >> 4, ln = lane & 15;
    const long n0 = (long)blockIdx.x * 128;

    // fused im2col stage: one 8-half segment per thread (128 rows x 4 segs)
    {
        int i = tid;
        int r = i >> 2, cseg = i & 3;
        long n = n0 + r;
        int b = (int)(n >> 10), y = (int)((n >> 5) & 31), xx = (int)(n & 31);
        unsigned int o[4] = {0, 0, 0, 0};
#pragma unroll
        for (int j = 0; j < 8; j++) {
            int k = cseg * 8 + j;
            if (k < 27) {
                int ci = k / 9, rem = k % 9;
                int ky = rem / 3, kx = rem % 3;
                int yy = y - 1 + ky, xc = xx - 1 + kx;
                if (yy >= 0 && yy < 32 && xc >= 0 && xc < 32) {
                    float v = x[((b * 3 + ci) * 32 + yy) * 32 + xc];
                    o[j >> 1] |= ((unsigned int)f2h(v)) << ((j & 1) * 16);
                }
            }
        }
        uint4 v4; v4.x = o[0]; v4.y = o[1]; v4.z = o[2]; v4.w = o[3];
        *(uint4*)(lds + r * LINE + cseg * 16) = v4;
    }
    __syncthreads();

    half8 af[2][4];
#pragma unroll
    for (int cv = 0; cv < 2; cv++)
#pragma unroll
    for (int m = 0; m < 4; m++)
        af[cv][m] = *(const half8*)(Wp + ((long)((cv * 8 + wm * 4 + m) * 64 + lane)) * 8);

    f32x4 accA[4][2], accB[4][2];
#pragma unroll
    for (int m = 0; m < 4; m++)
#pragma unroll
    for (int nf = 0; nf < 2; nf++) {
        accA[m][nf] = (f32x4){0.f, 0.f, 0.f, 0.f};
        accB[m][nf] = (f32x4){0.f, 0.f, 0.f, 0.f};
    }
#pragma unroll
    for (int nf = 0; nf < 2; nf++) {
        int r = wn * 32 + nf * 16 + ln;
        half8 b1 = *(const half8*)(lds + r * LINE + g * 16);
        half8 b2 = b1 * b1;
#pragma unroll
        for (int m = 0; m < 4; m++) {
            accA[m][nf] = __builtin_amdgcn_mfma_f32_16x16x32_f16(af[0][m], b1, accA[m][nf], 0, 0, 0);
            accB[m][nf] = __builtin_amdgcn_mfma_f32_16x16x32_f16(af[1][m], b2, accB[m][nf], 0, 0, 0);
        }
    }
    __syncthreads();
#pragma unroll
    for (int m = 0; m < 4; m++) {
        int cob = (wm * 4 + m) * 16 + g * 4;
#pragma unroll
        for (int nf = 0; nf < 2; nf++) {
            int nl = wn * 32 + nf * 16 + ln;
            unsigned int pk2[2];
#pragma unroll
            for (int r = 0; r < 4; r++) {
                float mm = accA[m][nf][r] + bias[cob + r];
                float vv = accB[m][nf][r];
                unsigned int hv = f2h(erff(mm * rsqrtf(vv + EPSV) * INV_SQRT2));
                if (r & 1) pk2[r >> 1] |= hv << 16; else pk2[r >> 1] = hv;
            }
            *(unsigned int*)(lds + (nl * TSTR + cob) * 2) = pk2[0];
            *(unsigned int*)(lds + (nl * TSTR + cob) * 2 + 4) = pk2[1];
        }
    }
    __syncthreads();
    for (int i = tid; i < 128 * 16; i += 512) {
        int nl = i >> 4, c8 = (i & 15) * 8;
        uint4 v = *(const uint4*)(lds + (nl * TSTR + c8) * 2);
        *(uint4*)(out + (n0 + nl) * 128 + c8) = v;
    }
}

// ---------------------------------------------------------------------------
// MFMA implicit-GEMM fused LRnet conv. NHWC fp16 input. 512 thr.
// Wave split MW x (8/MW) (template). T14 async-stage kept.
// HASBN=1: apply relu(x*bnsc[c]+bnsh[c]) during stage (padding stays 0).
// MODE 0/1/3/4 as before.
// ---------------------------------------------------------------------------
template<int Ci, int Hin, int Win, int Co, int Hout, int Wout, int STRIDE,
         int ROWS, int IPB, int NTILE, int CHUNK, int MTILE, int MW, int HASBN, int MODE>
__global__ __launch_bounds__(512) void conv_mfma(
    const unsigned short* __restrict__ in,
    const unsigned short* __restrict__ wpk,
    const float* __restrict__ bias,
    const float* __restrict__ ones_g,
    const float* __restrict__ epsb,
    const float* __restrict__ bnsc,
    const float* __restrict__ bnsh,
    void* __restrict__ outp)
{
    constexpr int BLK = 512;
    constexpr int PROWS = STRIDE * (ROWS - 1) + 3;
    constexpr int PW = Win + 2;
    constexpr int POS = IPB * PROWS * PW;
    constexpr int NCH32 = Ci / 32;
    constexpr int NCHL = Ci / CHUNK;
    constexpr int KS = CHUNK / 32;
    constexpr int MFg = Co / 16;
    constexpr int NF = NTILE / 16;
    constexpr int NW = 8 / MW;
    constexpr int WMF = MTILE / (16 * MW);
    constexpr int WNF = NF / NW;
    constexpr int CT = Co / MTILE;
    constexpr int RG = Hout / ROWS;
    constexpr int LINE = CHUNK * 2 + 16;
    constexpr int TSTR = MTILE + 8;
    constexpr int PASSN = (NTILE < 128) ? NTILE : 128;
    constexpr int NPASS = (MODE == 4) ? 0 : NTILE / PASSN;
    constexpr int STAGE_B = POS * LINE;
    constexpr int TR_B = (MODE == 4) ? 0 : PASSN * TSTR * 2;
    constexpr int LDS_B = STAGE_B > TR_B ? STAGE_B : TR_B;
    constexpr int NV = POS * (CHUNK / 8);
    constexpr int NLD = (NV + BLK - 1) / BLK;
    static_assert(8 % CT == 0, "ct swizzle");
    static_assert(WNF * NW == NF, "wnf");
    static_assert(WMF * 16 * MW == MTILE, "wmf");
    static_assert(NCHL * CHUNK == Ci, "chunk");
    static_assert(LDS_B <= 65536, "lds");
    __shared__ char lds[LDS_B];

    const int tid = threadIdx.x;
    const int lane = tid & 63;
    const int wv = tid >> 6;
    const int wm = wv % MW, wn = wv / MW;
    const int g = lane >> 4, ln = lane & 15;

    const int bid = blockIdx.x;
    const int xcd = bid & 7;
    constexpr int XPC = 8 / CT;
    const int ct = xcd % CT;
    const int nt = (bid >> 3) * XPC + xcd / CT;
    const int b0 = (nt / RG) * IPB;
    const int y0 = (nt % RG) * ROWS;

    int pbase[WNF];
#pragma unroll
    for (int nf = 0; nf < WNF; nf++) {
        int n = (wn * WNF + nf) * 16 + ln;
        int img = n / (ROWS * Wout);
        int rem = n % (ROWS * Wout);
        int yr = rem / Wout, xo = rem % Wout;
        pbase[nf] = (img * PROWS + STRIDE * yr) * PW + STRIDE * xo;
    }

    // ---- precompute per-thread stage addresses (ch-invariant) ----
    const unsigned short* gsrc[NLD];
    int ldst[NLD];
    int cseg[NLD];
#pragma unroll
    for (int j = 0; j < NLD; j++) {
        int i = tid + j * BLK;
        gsrc[j] = nullptr; ldst[j] = 0; cseg[j] = 0;
        if (i < NV) {
            int p = i / (CHUNK / 8), c = i % (CHUNK / 8);
            int img = p / (PROWS * PW);
            int r = p % (PROWS * PW);
            int prow = r / PW, px = r % PW;
            int yin = STRIDE * y0 - 1 + prow;
            int xin = px - 1;
            ldst[j] = p * LINE + c * 16;
            cseg[j] = c * 8;
            if (yin >= 0 && yin < Hin && xin >= 0 && xin < Win)
                gsrc[j] = in + (((long)(b0 + img) * Hin + yin) * Win + xin) * Ci + c * 8;
        }
    }

    f32x4 accA[WMF][WNF], accB[WMF][WNF];
#pragma unroll
    for (int mf = 0; mf < WMF; mf++)
#pragma unroll
    for (int nf = 0; nf < WNF; nf++) {
        accA[mf][nf] = (f32x4){0.f, 0.f, 0.f, 0.f};
        accB[mf][nf] = (f32x4){0.f, 0.f, 0.f, 0.f};
    }

    const unsigned short* wbase = wpk + ((long)(ct * (MTILE / 16) + wm * WMF) * 64 + lane) * 8;

    // issue chunk-0 loads
    uint4 regs[NLD];
#pragma unroll
    for (int j = 0; j < NLD; j++) {
        uint4 v; v.x = 0; v.y = 0; v.z = 0; v.w = 0;
        if (tid + j * BLK < NV && gsrc[j]) v = *(const uint4*)(gsrc[j]);
        regs[j] = v;
    }

    for (int ch = 0; ch < NCHL; ch++) {
        // ---- write chunk ch (BN fused if HASBN; padding stays zero) ----
#pragma unroll
        for (int j = 0; j < NLD; j++)
            if (tid + j * BLK < NV) {
                uint4 v = regs[j];
                if constexpr (HASBN) {
                    if (gsrc[j]) {
                        int cb = ch * CHUNK + cseg[j];
                        unsigned int* vp = (unsigned int*)&v;
#pragma unroll
                        for (int e = 0; e < 4; e++) {
                            float lo = h2f((unsigned short)(vp[e] & 0xffffu));
                            float hi = h2f((unsigned short)(vp[e] >> 16));
                            lo = fmaf(lo, bnsc[cb + 2 * e], bnsh[cb + 2 * e]);
                            lo = lo > 0.f ? lo : 0.f;
                            hi = fmaf(hi, bnsc[cb + 2 * e + 1], bnsh[cb + 2 * e + 1]);
                            hi = hi > 0.f ? hi : 0.f;
                            vp[e] = (unsigned int)f2h(lo) | (((unsigned int)f2h(hi)) << 16);
                        }
                    }
                }
                *(uint4*)(lds + ldst[j]) = v;
            }
        __syncthreads();
        // ---- issue chunk ch+1 loads ----
        if (ch + 1 < NCHL) {
#pragma unroll
            for (int j = 0; j < NLD; j++) {
                uint4 v; v.x = 0; v.y = 0; v.z = 0; v.w = 0;
                if (tid + j * BLK < NV && gsrc[j])
                    v = *(const uint4*)(gsrc[j] + (long)(ch + 1) * CHUNK);
                regs[j] = v;
            }
        }
        // ---- compute chunk ch ----
#pragma unroll 3
        for (int pos = 0; pos < 9; pos++) {
            const int ky = pos / 3, kx = pos % 3;
#pragma unroll
            for (int ks = 0; ks < KS; ks++) {
                const int ch32 = ch * KS + ks;
                half8 af[2][WMF];
#pragma unroll
                for (int cv = 0; cv < 2; cv++)
#pragma unroll
                for (int mf = 0; mf < WMF; mf++)
                    af[cv][mf] = *(const half8*)(wbase +
                        ((long)(((cv * 9 + pos) * NCH32 + ch32) * MFg + mf)) * 512);
#pragma unroll
                for (int nf = 0; nf < WNF; nf++) {
                    int po = (pbase[nf] + ky * PW + kx) * LINE + ks * 64 + g * 16;
                    half8 b1 = *(const half8*)(lds + po);
                    half8 b2 = b1 * b1;               // v_pk_mul_f16
#pragma unroll
                    for (int mf = 0; mf < WMF; mf++) {
                        accA[mf][nf] = __builtin_amdgcn_mfma_f32_16x16x32_f16(af[0][mf], b1, accA[mf][nf], 0, 0, 0);
                        accB[mf][nf] = __builtin_amdgcn_mfma_f32_16x16x32_f16(af[1][mf], b2, accB[mf][nf], 0, 0, 0);
                    }
                }
            }
        }
        __syncthreads();
    }

    // ---- epilogue ----
    if constexpr (MODE == 4) {
        unsigned short* out = (unsigned short*)outp;
#pragma unroll
        for (int mf = 0; mf < WMF; mf++) {
            int co = ct * MTILE + (wm * WMF + mf) * 16 + g * 4;
#pragma unroll
            for (int nf = 0; nf < WNF; nf++) {
                int n = (wn * WNF + nf) * 16 + ln;
                int img = n / (ROWS * Wout), rem = n % (ROWS * Wout);
                int y = y0 + rem / Wout, x = rem % Wout;
                int b = b0 + img;
#pragma unroll
                for (int r = 0; r < 4; r++) {
                    int c = co + r;
                    float m = accA[mf][nf][r] + bias[c];
                    float v = ones_g[(c * Hout + y) * Wout + x] - accB[mf][nf][r];
                    long oi = (((long)b * Co + c) * Hout + y) * Wout + x;
                    out[oi] = f2h(m + sqrtf(v + EPSV) * epsb[oi]);
                }
            }
        }
    } else {
        unsigned short* out = (unsigned short*)outp;
#pragma unroll
        for (int pass = 0; pass < NPASS; pass++) {
            __syncthreads();
#pragma unroll
            for (int mf = 0; mf < WMF; mf++) {
                int cob = (wm * WMF + mf) * 16 + g * 4;
                int cg = ct * MTILE + cob;
#pragma unroll
                for (int nf = 0; nf < WNF; nf++) {
                    int nb = (wn * WNF + nf) * 16;
                    if (nb < pass * PASSN || nb >= (pass + 1) * PASSN) continue;
                    int n = nb + ln;
                    int img = n / (ROWS * Wout), rem = n % (ROWS * Wout);
                    int y = y0 + rem / Wout, x = rem % Wout;
                    int b = b0 + img;
                    unsigned int pk2[2];
#pragma unroll
                    for (int r = 0; r < 4; r++) {
                        int c = cg + r;
                        float m = accA[mf][nf][r] + bias[c];
                        float val;
                        if constexpr (MODE == 0) {
                            val = erff(m * rsqrtf(accB[mf][nf][r] + EPSV) * INV_SQRT2);
                        } else if constexpr (MODE == 1) {
                            float v = ones_g[(c * Hout + y) * Wout + x] - accB[mf][nf][r];
                            val = erff(m * rsqrtf(v + EPSV) * INV_SQRT2);
                        } else { // MODE 3
                            float v = ones_g[(c * Hout + y) * Wout + x] - accB[mf][nf][r];
                            float ev = epsb[(((long)b * Co + c) * Hout + y) * Wout + x];
                            val = m + sqrtf(v + EPSV) * ev;
                        }
                        unsigned int hv = f2h(val);
                        if (r & 1) pk2[r >> 1] |= hv << 16; else pk2[r >> 1] = hv;
                    }
                    int nl = n - pass * PASSN;
                    *(unsigned int*)(lds + (nl * TSTR + cob) * 2) = pk2[0];
                    *(unsigned int*)(lds + (nl * TSTR + cob) * 2 + 4) = pk2[1];
                }
            }
            __syncthreads();
            for (int i = tid; i < PASSN * (MTILE / 8); i += BLK) {
                int nl = i / (MTILE / 8);
                int n = pass * PASSN + nl;
                int c8 = (i % (MTILE / 8)) * 8;
                int img = n / (ROWS * Wout), rem = n % (ROWS * Wout);
                int y = y0 + rem / Wout, x = rem % Wout;
                int b = b0 + img;
                uint4 val = *(const uint4*)(lds + (nl * TSTR + c8) * 2);
                long oa = (((long)b * Hout + y) * Wout + x) * Co + ct * MTILE + c8;
                *(uint4*)(out + oa) = val;
            }
        }
    }
}

// ---------------------------------------------------------------------------
// BatchNorm stats (fp16 activations, partial-sum based, no atomics)
// ---------------------------------------------------------------------------
__global__ void bn_part_nhwc(const unsigned short* __restrict__ h, float* __restrict__ part,
                             int C, int rpc) {
    int c = threadIdx.x;
    long r0 = (long)blockIdx.x * rpc;
    float s = 0.f, s2 = 0.f;
    for (int r = 0; r < rpc; r++) {
        float v = h2f(h[(r0 + r) * C + c]);
        s += v; s2 += v * v;
    }
    part[(long)blockIdx.x * 2 * C + c] = s;
    part[(long)blockIdx.x * 2 * C + C + c] = s2;
}

__global__ void bn_part_nchw(const unsigned short* __restrict__ h, float* __restrict__ part,
                             int ipc) {
    int c = threadIdx.x;
    int b0 = blockIdx.x * ipc;
    float s = 0.f, s2 = 0.f;
    for (int b = 0; b < ipc; b++) {
        const unsigned short* p = h + ((long)(b0 + b) * 512 + c) * 16;
        uint4 v0 = *(const uint4*)p;
        uint4 v1 = *(const uint4*)(p + 8);
        unsigned int* vp0 = (unsigned int*)&v0;
        unsigned int* vp1 = (unsigned int*)&v1;
#pragma unroll
        for (int e = 0; e < 4; e++) {
            float a = h2f((unsigned short)(vp0[e] & 0xffffu)), bb = h2f((unsigned short)(vp0[e] >> 16));
            float cc = h2f((unsigned short)(vp1[e] & 0xffffu)), d = h2f((unsigned short)(vp1[e] >> 16));
            s += a + bb + cc + d;
            s2 += a * a + bb * bb + cc * cc + d * d;
        }
    }
    part[(long)blockIdx.x * 1024 + c] = s;
    part[(long)blockIdx.x * 1024 + 512 + c] = s2;
}

__global__ void bn_fin(const float* __restrict__ part, const float* __restrict__ gamma,
                       const float* __restrict__ beta, float* __restrict__ sc,
                       float* __restrict__ sh, int C, int chunks, float invN) {
    int c = blockIdx.x * 256 + threadIdx.x;
    if (c >= C) return;
    float s = 0.f, s2 = 0.f;
    for (int j = 0; j < chunks; j++) {
        s += part[(long)j * 2 * C + c];
        s2 += part[(long)j * 2 * C + C + c];
    }
    float mean = s * invN;
    float var = s2 * invN - mean * mean;
    float k = gamma[c] * rsqrtf(var + BNEPS);
    sc[c] = k;
    sh[c] = beta[c] - mean * k;
}

// ---------------------------------------------------------------------------
// FC1 fp16 MFMA split-K. BN6 (sc/sh + relu) fused into A-stage.
// ---------------------------------------------------------------------------
__global__ __launch_bounds__(256) void fc1_mfma(const unsigned short* __restrict__ Ab,
                                                const unsigned short* __restrict__ Wp,
                                                const float* __restrict__ sc6,
                                                const float* __restrict__ sh6,
                                                float* __restrict__ pbuf) {
    __shared__ char lds[2 * 64 * 80];
    const int tid = threadIdx.x;
    const int lane = tid & 63;
    const int wv = tid >> 6;
    const int g = lane >> 4, ln = lane & 15;
    const int ot = blockIdx.x, bt = blockIdx.y, s = blockIdx.z;
    const int b0 = bt * 64;
    const int k0g = s * 1024;

    f32x4 acc[2][4];
#pragma unroll
    for (int c = 0; c < 2; c++)
#pragma unroll
    for (int nf = 0; nf < 4; nf++) acc[c][nf] = (f32x4){0.f, 0.f, 0.f, 0.f};

    for (int k0 = 0; k0 < 1024; k0 += 64) {
        __syncthreads();
        for (int i = tid; i < 512; i += 256) {
            int row = i >> 3, kk = (i >> 2) & 1, seg = i & 3;
            int kidx = k0g + k0 + kk * 32 + seg * 8;
            uint4 v = *(const uint4*)(Ab + ((long)(b0 + row) * 8192 + kidx));
            // fused BN6 + relu (one channel per 8-half load)
            int c = kidx >> 4;
            float kc = sc6[c], tc = sh6[c];
            unsigned int* vp = (unsigned int*)&v;
#pragma unroll
            for (int e = 0; e < 4; e++) {
                float lo = h2f((unsigned short)(vp[e] & 0xffffu));
                float hi = h2f((unsigned short)(vp[e] >> 16));
                lo = fmaf(lo, kc, tc); lo = lo > 0.f ? lo : 0.f;
                hi = fmaf(hi, kc, tc); hi = hi > 0.f ? hi : 0.f;
                vp[e] = (unsigned int)f2h(lo) | (((unsigned int)f2h(hi)) << 16);
            }
            *(uint4*)(lds + (kk * 64 + row) * 80 + seg * 16) = v;
        }
        __syncthreads();
#pragma unroll
        for (int kk = 0; kk < 2; kk++) {
            int kt = (k0g + k0) / 32 + kk;
            half8 af[2];
#pragma unroll
            for (int c = 0; c < 2; c++) {
                int mf = ot * 8 + wv * 2 + c;
                af[c] = *(const half8*)(Wp + (((long)kt * 64 + mf) * 64 + lane) * 8);
            }
            half8 bf[4];
#pragma unroll
            for (int nf = 0; nf < 4; nf++)
                bf[nf] = *(const half8*)(lds + (kk * 64 + nf * 16 + ln) * 80 + g * 16);
#pragma unroll
            for (int c = 0; c < 2; c++)
#pragma unroll
            for (int nf = 0; nf < 4; nf++)
                acc[c][nf] = __builtin_amdgcn_mfma_f32_16x16x32_f16(af[c], bf[nf], acc[c][nf], 0, 0, 0);
        }
    }
#pragma unroll
    for (int c = 0; c < 2; c++) {
        int o = ot * 128 + (wv * 2 + c) * 16 + g * 4;
#pragma unroll
        for (int nf = 0; nf < 4; nf++) {
            int b = b0 + nf * 16 + ln;
            *(f32x4*)(pbuf + ((long)s * 256 + b) * 1024 + o) = acc[c][nf];
        }
    }
}

// FC2 with fused fc1 split-K reduction + bias + relu (bit-identical to old chain)
__global__ void fc2_k(const float* __restrict__ pbuf, const float* __restrict__ fc1b,
                      const float* __restrict__ W, const float* __restrict__ b2,
                      float* __restrict__ out) {
    int bb = blockIdx.x;
    int tid = threadIdx.x;
    float acc[10];
#pragma unroll
    for (int o = 0; o < 10; o++) acc[o] = 0.f;
    for (int k = tid; k < 1024; k += 256) {
        float s = 0.f;
#pragma unroll
        for (int j = 0; j < 8; j++) s += pbuf[(long)j * 262144 + bb * 1024 + k];
        s += fc1b[k];
        float a = s > 0.f ? s : 0.f;
#pragma unroll
        for (int o = 0; o < 10; o++) acc[o] = fmaf(a, W[o * 1024 + k], acc[o]);
    }
#pragma unroll
    for (int o = 0; o < 10; o++)
        for (int off = 32; off > 0; off >>= 1) acc[o] += __shfl_down(acc[o], off);
    __shared__ float red[10][4];
    int wid = tid >> 6, lane = tid & 63;
    if (lane == 0) {
#pragma unroll
        for (int o = 0; o < 10; o++) red[o][wid] = acc[o];
    }
    __syncthreads();
    if (tid < 10)
        out[bb * 10 + tid] = red[tid][0] + red[tid][1] + red[tid][2] + red[tid][3] + b2[tid];
}

// ---------------------------------------------------------------------------
extern "C" void kernel_launch(void* const* d_in, const int* in_sizes, int n_in,
                              void* d_out, int out_size, void* d_ws, size_t ws_size,
                              hipStream_t stream) {
    const float* x  = (const float*)d_in[0];
    const float* a1 = (const float*)d_in[1];  const float* b1 = (const float*)d_in[2];  const float* c1 = (const float*)d_in[3];
    const float* a2 = (const float*)d_in[4];  const float* b2 = (const float*)d_in[5];  const float* c2 = (const float*)d_in[6];
    const float* a3 = (const float*)d_in[7];  const float* b3 = (const float*)d_in[8];  const float* c3 = (const float*)d_in[9];
    const float* a4 = (const float*)d_in[10]; const float* b4 = (const float*)d_in[11]; const float* c4 = (const float*)d_in[12];
    const float* a5 = (const float*)d_in[13]; const float* b5 = (const float*)d_in[14]; const float* c5 = (const float*)d_in[15];
    const float* a6 = (const float*)d_in[16]; const float* b6 = (const float*)d_in[17]; const float* c6 = (const float*)d_in[18];
    const float* g3 = (const float*)d_in[19]; const float* be3 = (const float*)d_in[20];
    const float* g6 = (const float*)d_in[21]; const float* be6 = (const float*)d_in[22];
    const float* fc1w = (const float*)d_in[23]; const float* fc1b = (const float*)d_in[24];
    const float* fc2w = (const float*)d_in[25]; const float* fc2b = (const float*)d_in[26];
    const float* eps3 = (const float*)d_in[27]; const float* eps6 = (const float*)d_in[28];
    (void)in_sizes; (void)n_in; (void)out_size; (void)ws_size;

    float* w = (float*)d_ws;
    size_t off = 0;
    auto alloc = [&](size_t n) { float* p = w + off; off += n; return p; };
    unsigned short* pk2 = (unsigned short*)alloc(147456);
    unsigned short* pk3 = (unsigned short*)alloc(294912);
    unsigned short* pk4 = (unsigned short*)alloc(589824);
    unsigned short* pk5 = (unsigned short*)alloc(1179648);
    unsigned short* pk6 = (unsigned short*)alloc(2359296);
    unsigned short* pkL1 = (unsigned short*)alloc(4096);
    float* ss2 = alloc(1152); float* ss3 = alloc(2304);
    float* ss5 = alloc(4608); float* ss6 = alloc(4608);
    float* og2 = alloc(32768); float* og3 = alloc(65536);
    float* og5 = alloc(32768); float* og6 = alloc(8192);
    float* part3 = alloc(131072);
    float* part6 = alloc(65536);
    float* sc3 = alloc(256); float* sh3 = alloc(256);
    float* sc6 = alloc(512); float* sh6 = alloc(512);
    float* A  = alloc(16777216);
    float* Bb = alloc(4194304);
    float* Cc = alloc(8388608);
    float* Dd = alloc(2097152);
    float* Ee = alloc(4194304);

    unsigned short* ex1 = (unsigned short*)A;
    unsigned short* pkF = (unsigned short*)A;
    float*          pbuf = A + 4194304;
    unsigned short* ex2 = (unsigned short*)Bb;
    unsigned short* h6b = (unsigned short*)(Bb + 524288);
    unsigned short* h3b = (unsigned short*)Cc;
    unsigned short* ex4 = (unsigned short*)Dd;
    unsigned short* ex5 = (unsigned short*)Ee;

    // ---- prep (fused) ----
    prep_all<<<2588, 256, 0, stream>>>(a1, b1, pkL1, a2, b2, pk2, a3, b3, pk3,
                                       a4, b4, pk4, a5, b5, pk5, a6, b6, pk6,
                                       ss2, ss3, ss5, ss6);
    prep_ones_all<<<544, 256, 0, stream>>>(ss2, ss3, ss5, ss6, og2, og3, og5, og6);

    // ---- network ----
    // L1: fused im2col + MFMA GEMM -> ex1 [256,32,32,128] NHWC fp16
    conv1_mfma<<<2048, 512, 0, stream>>>(x, pkL1, c1, ex1);
    // L2  (MW=4, MTILE=128, N-split: ROWS=4 -> NTILE=64, grid 1024)
    conv_mfma<128,32,32,128,16,16,2, 4,1,64,32,128,4,0,1><<<1024, 512, 0, stream>>>(ex1, pk2, c2, og2, nullptr, nullptr, nullptr, ex2);
    // L3  (MW=8: NW=1, no wn weight duplication; NTILE=128, CHUNK=128, grid 1024)
    conv_mfma<128,16,16,256,16,16,1, 8,1,128,128,128,8,0,3><<<1024, 512, 0, stream>>>(ex2, pk3, c3, og3, eps3, nullptr, nullptr, h3b);
    prep_fc1<<<4096, 256, 0, stream>>>(fc1w, pkF);
    // BN3 stats (pre-activation, matches reference)
    bn_part_nhwc<<<256, 256, 0, stream>>>(h3b, part3, 256, 256);
    bn_fin<<<1, 256, 0, stream>>>(part3, g3, be3, sc3, sh3, 256, 256, 1.f / 65536.f);
    // L4  (MW=8: NW=1, no wn weight duplication; BN3 fused into stage)
    conv_mfma<256,16,16,256, 8, 8,2, 8,1,64,32,128,8,1,0><<<512, 512, 0, stream>>>(h3b, pk4, c4, nullptr, nullptr, sc3, sh3, ex4);
    // L5  (MW=4, MTILE=64, grid 1024)
    conv_mfma<256, 8, 8,512, 8, 8,1, 8,2,128,32,64,4,0,1><<<1024, 512, 0, stream>>>(ex4, pk5, c5, og5, nullptr, nullptr, nullptr, ex5);
    // L6  (MW=4, MTILE=64)
    conv_mfma<512, 8, 8,512, 4, 4,2, 4,4,64,32,64,4,0,4><<<512, 512, 0, stream>>>(ex5, pk6, c6, og6, eps6, nullptr, nullptr, h6b);
    // BN6 stats
    bn_part_nchw<<<64, 512, 0, stream>>>(h6b, part6, 4);
    bn_fin<<<2, 256, 0, stream>>>(part6, g6, be6, sc6, sh6, 512, 64, 1.f / 4096.f);
    // FC1 (BN6 fused into A-stage) + FC2 (fc1 reduction fused)
    fc1_mfma<<<dim3(8, 4, 8), 256, 0, stream>>>(h6b, pkF, sc6, sh6, pbuf);
    fc2_k<<<256, 256, 0, stream>>>(pbuf, fc1b, fc2w, fc2b, (float*)d_out);
}

// Round 24
// 652.103 us; speedup vs baseline: 1.0147x; 1.0147x over previous
//
#include <hip/hip_runtime.h>
#include <hip/hip_bf16.h>
#include <math.h>

#define EPSV 1e-10f
#define BNEPS 1e-5f
#define INV_SQRT2 0.70710678118654752440f

typedef __attribute__((ext_vector_type(8))) short short8;
typedef __attribute__((ext_vector_type(4))) float f32x4;
typedef _Float16 half8 __attribute__((ext_vector_type(8)));

__device__ __forceinline__ unsigned short f2h(float f) {
    _Float16 h = (_Float16)f;                      // RNE
    return __builtin_bit_cast(unsigned short, h);
}
__device__ __forceinline__ float h2f(unsigned short u) {
    _Float16 h = __builtin_bit_cast(_Float16, u);
    return (float)h;
}

// ---------------------------------------------------------------------------
// Fused prep: 5x prep_pack + packL1 + 4x prep_s in ONE kernel (disjoint outputs)
// ---------------------------------------------------------------------------
__device__ __forceinline__ void pack_one(const float* __restrict__ a,
        const float* __restrict__ b, unsigned short* __restrict__ pk,
        int Ci, int Co, int ver2, int idx, int total) {
    if (idx >= total) return;
    int lane = idx & 63;
    int MFg = Co >> 4, NCH = Ci >> 5;
    int mfch = idx >> 6;
    int mf = mfch % MFg;
    int chpos = mfch / MFg;
    int ch = chpos % NCH;
    int pos = chpos / NCH;
    int co = mf * 16 + (lane & 15);
    int cib = ch * 32 + (lane >> 4) * 8;
    unsigned int wa[4], wb[4];
#pragma unroll
    for (int j = 0; j < 8; j++) {
        long s = ((long)co * Ci + cib + j) * 9 + pos;
        float p0 = 1.f / (1.f + expf(-a[s]));
        float sb = 1.f / (1.f + expf(-b[s]));
        float p1 = (1.f - p0) * sb;
        float ew = 2.f * p1 - (1.f - p0);
        float ew2 = 1.f - p0;
        unsigned int ha = f2h(ew);
        unsigned int hb = f2h(ver2 ? ew * ew : ew2 - ew * ew);
        if (j & 1) { wa[j >> 1] |= ha << 16; wb[j >> 1] |= hb << 16; }
        else       { wa[j >> 1] = ha;        wb[j >> 1] = hb; }
    }
    long b0 = (((long)(0 * 9 + pos) * NCH + ch) * MFg + mf) * 64 + lane;
    long b1 = (((long)(1 * 9 + pos) * NCH + ch) * MFg + mf) * 64 + lane;
    uint4 va; va.x = wa[0]; va.y = wa[1]; va.z = wa[2]; va.w = wa[3];
    uint4 vb; vb.x = wb[0]; vb.y = wb[1]; vb.z = wb[2]; vb.w = wb[3];
    *(uint4*)(pk + b0 * 8) = va;
    *(uint4*)(pk + b1 * 8) = vb;
}

__device__ __forceinline__ void s_one(const float* __restrict__ alpha,
        float* __restrict__ s, int Ci, int co, int lane) {
    float acc[9];
#pragma unroll
    for (int k = 0; k < 9; k++) acc[k] = 0.f;
    for (int ci = lane; ci < Ci; ci += 64) {
        const float* p = alpha + ((long)co * Ci + ci) * 9;
#pragma unroll
        for (int k = 0; k < 9; k++) acc[k] += 1.f / (1.f + expf(p[k]));
    }
#pragma unroll
    for (int k = 0; k < 9; k++) {
        for (int off = 32; off > 0; off >>= 1) acc[k] += __shfl_down(acc[k], off);
    }
    if (lane == 0) {
#pragma unroll
        for (int k = 0; k < 9; k++) s[co * 9 + k] = acc[k];
    }
}

// grid 2588 x 256
__global__ void prep_all(
    const float* __restrict__ a1, const float* __restrict__ b1, unsigned short* __restrict__ pkL1,
    const float* __restrict__ a2, const float* __restrict__ b2, unsigned short* __restrict__ pk2,
    const float* __restrict__ a3, const float* __restrict__ b3, unsigned short* __restrict__ pk3,
    const float* __restrict__ a4, const float* __restrict__ b4, unsigned short* __restrict__ pk4,
    const float* __restrict__ a5, const float* __restrict__ b5, unsigned short* __restrict__ pk5,
    const float* __restrict__ a6, const float* __restrict__ b6, unsigned short* __restrict__ pk6,
    float* __restrict__ ss2, float* __restrict__ ss3,
    float* __restrict__ ss5, float* __restrict__ ss6)
{
    int bid = blockIdx.x;
    int tid = threadIdx.x;
    if (bid < 72) {
        pack_one(a2, b2, pk2, 128, 128, 1, bid * 256 + tid, 18432);
    } else if (bid < 216) {
        pack_one(a3, b3, pk3, 128, 256, 1, (bid - 72) * 256 + tid, 36864);
    } else if (bid < 504) {
        pack_one(a4, b4, pk4, 256, 256, 0, (bid - 216) * 256 + tid, 73728);
    } else if (bid < 1080) {
        pack_one(a5, b5, pk5, 256, 512, 1, (bid - 504) * 256 + tid, 147456);
    } else if (bid < 2232) {
        pack_one(a6, b6, pk6, 512, 512, 1, (bid - 1080) * 256 + tid, 294912);
    } else if (bid < 2236) {
        // packL1: prep_w math inlined (L1 is lrconv: WB = var_w)
        int idx = (bid - 2232) * 256 + tid;   // 1024 total
        if (idx >= 1024) return;
        int lane = idx & 63;
        int mf = (idx >> 6) & 7;
        int cv = idx >> 9;
        int co = mf * 16 + (lane & 15);
        int k0 = (lane >> 4) * 8;
        unsigned int o[4] = {0, 0, 0, 0};
#pragma unroll
        for (int j = 0; j < 8; j++) {
            int k = k0 + j;
            if (k < 27) {
                long sgi = (long)co * 27 + k;
                float p0 = 1.f / (1.f + expf(-a1[sgi]));
                float sb = 1.f / (1.f + expf(-b1[sgi]));
                float p1 = (1.f - p0) * sb;
                float ew = 2.f * p1 - (1.f - p0);
                float ew2 = 1.f - p0;
                float val = cv ? (ew2 - ew * ew) : ew;
                unsigned int h = f2h(val);
                o[j >> 1] |= h << ((j & 1) * 16);
            }
        }
        uint4 v; v.x = o[0]; v.y = o[1]; v.z = o[2]; v.w = o[3];
        *(uint4*)(pkL1 + (long)idx * 8) = v;
    } else {
        // prep_s: 4 co per block (64-lane groups); 1408 co total -> 352 blocks
        int cog = (bid - 2236) * 4 + (tid >> 6);
        int lane = tid & 63;
        if (cog < 128)       s_one(a2, ss2, 128, cog, lane);
        else if (cog < 384)  s_one(a3, ss3, 128, cog - 128, lane);
        else if (cog < 896)  s_one(a5, ss5, 256, cog - 384, lane);
        else if (cog < 1408) s_one(a6, ss6, 512, cog - 896, lane);
    }
}

// grid 544 x 256: all 4 ones-grids
__device__ __forceinline__ void ones_one(const float* __restrict__ ssum, float* __restrict__ og,
        int Hout, int Wout, int Hin, int Win, int stride, int idx) {
    int x = idx % Wout, y = (idx / Wout) % Hout, co = idx / (Wout * Hout);
    float s = 0.f;
    for (int ky = 0; ky < 3; ky++) {
        int yi = stride * y - 1 + ky;
        if (yi < 0 || yi >= Hin) continue;
        for (int kx = 0; kx < 3; kx++) {
            int xi = stride * x - 1 + kx;
            if (xi < 0 || xi >= Win) continue;
            s += ssum[co * 9 + ky * 3 + kx];
        }
    }
    og[idx] = s;
}

__global__ void prep_ones_all(const float* __restrict__ ss2, const float* __restrict__ ss3,
                              const float* __restrict__ ss5, const float* __restrict__ ss6,
                              float* __restrict__ og2, float* __restrict__ og3,
                              float* __restrict__ og5, float* __restrict__ og6) {
    int idx = blockIdx.x * 256 + threadIdx.x;     // 139264 total
    if (idx < 32768)        ones_one(ss2, og2, 16, 16, 32, 32, 2, idx);
    else if (idx < 98304)   ones_one(ss3, og3, 16, 16, 16, 16, 1, idx - 32768);
    else if (idx < 131072)  ones_one(ss5, og5, 8, 8, 8, 8, 1, idx - 98304);
    else if (idx < 139264)  ones_one(ss6, og6, 4, 4, 8, 8, 2, idx - 131072);
}

// ---------------------------------------------------------------------------
// FC1 weight pack: fp32 [1024][8192] -> fp16 A-fragment order
// ---------------------------------------------------------------------------
__global__ void prep_fc1(const float* __restrict__ W, unsigned short* __restrict__ pk) {
    int idx = blockIdx.x * 256 + threadIdx.x;
    int lane = idx & 63;
    int mf = (idx >> 6) & 63;
    int kt = idx >> 12;
    int o = mf * 16 + (lane & 15);
    long k = (long)kt * 32 + (lane >> 4) * 8;
    const float* src = W + (long)o * 8192 + k;
    float4 f0 = *(const float4*)src;
    float4 f1 = *(const float4*)(src + 4);
    uint4 v;
    v.x = (unsigned)f2h(f0.x) | ((unsigned)f2h(f0.y) << 16);
    v.y = (unsigned)f2h(f0.z) | ((unsigned)f2h(f0.w) << 16);
    v.z = (unsigned)f2h(f1.x) | ((unsigned)f2h(f1.y) << 16);
    v.w = (unsigned)f2h(f1.z) | ((unsigned)f2h(f1.w) << 16);
    *(uint4*)(pk + (long)idx * 8) = v;
}

// ---------------------------------------------------------------------------
// L1 MFMA GEMM with fused im2col (gathers window directly from fp32 x)
// ---------------------------------------------------------------------------
__global__ __launch_bounds__(512) void conv1_mfma(const float* __restrict__ x,
        const unsigned short* __restrict__ Wp, const float* __restrict__ bias,
        unsigned short* __restrict__ out) {
    constexpr int LINE = 80;
    constexpr int TSTR = 136;
    __shared__ char lds[128 * TSTR * 2];
    const int tid = threadIdx.x, lane = tid & 63, wv = tid >> 6;
    const int wm = wv & 1, wn = wv >> 1;
    const int g = lane >> 4, ln = lane & 15;
    const long n0 = (long)blockIdx.x * 128;

    // fused im2col stage: one 8-half segment per thread (128 rows x 4 segs)
    {
        int i = tid;
        int r = i >> 2, cseg = i & 3;
        long n = n0 + r;
        int b = (int)(n >> 10), y = (int)((n >> 5) & 31), xx = (int)(n & 31);
        unsigned int o[4] = {0, 0, 0, 0};
#pragma unroll
        for (int j = 0; j < 8; j++) {
            int k = cseg * 8 + j;
            if (k < 27) {
                int ci = k / 9, rem = k % 9;
                int ky = rem / 3, kx = rem % 3;
                int yy = y - 1 + ky, xc = xx - 1 + kx;
                if (yy >= 0 && yy < 32 && xc >= 0 && xc < 32) {
                    float v = x[((b * 3 + ci) * 32 + yy) * 32 + xc];
                    o[j >> 1] |= ((unsigned int)f2h(v)) << ((j & 1) * 16);
                }
            }
        }
        uint4 v4; v4.x = o[0]; v4.y = o[1]; v4.z = o[2]; v4.w = o[3];
        *(uint4*)(lds + r * LINE + cseg * 16) = v4;
    }
    __syncthreads();

    half8 af[2][4];
#pragma unroll
    for (int cv = 0; cv < 2; cv++)
#pragma unroll
    for (int m = 0; m < 4; m++)
        af[cv][m] = *(const half8*)(Wp + ((long)((cv * 8 + wm * 4 + m) * 64 + lane)) * 8);

    f32x4 accA[4][2], accB[4][2];
#pragma unroll
    for (int m = 0; m < 4; m++)
#pragma unroll
    for (int nf = 0; nf < 2; nf++) {
        accA[m][nf] = (f32x4){0.f, 0.f, 0.f, 0.f};
        accB[m][nf] = (f32x4){0.f, 0.f, 0.f, 0.f};
    }
#pragma unroll
    for (int nf = 0; nf < 2; nf++) {
        int r = wn * 32 + nf * 16 + ln;
        half8 b1 = *(const half8*)(lds + r * LINE + g * 16);
        half8 b2 = b1 * b1;
#pragma unroll
        for (int m = 0; m < 4; m++) {
            accA[m][nf] = __builtin_amdgcn_mfma_f32_16x16x32_f16(af[0][m], b1, accA[m][nf], 0, 0, 0);
            accB[m][nf] = __builtin_amdgcn_mfma_f32_16x16x32_f16(af[1][m], b2, accB[m][nf], 0, 0, 0);
        }
    }
    __syncthreads();
#pragma unroll
    for (int m = 0; m < 4; m++) {
        int cob = (wm * 4 + m) * 16 + g * 4;
#pragma unroll
        for (int nf = 0; nf < 2; nf++) {
            int nl = wn * 32 + nf * 16 + ln;
            unsigned int pk2[2];
#pragma unroll
            for (int r = 0; r < 4; r++) {
                float mm = accA[m][nf][r] + bias[cob + r];
                float vv = accB[m][nf][r];
                unsigned int hv = f2h(erff(mm * rsqrtf(vv + EPSV) * INV_SQRT2));
                if (r & 1) pk2[r >> 1] |= hv << 16; else pk2[r >> 1] = hv;
            }
            *(unsigned int*)(lds + (nl * TSTR + cob) * 2) = pk2[0];
            *(unsigned int*)(lds + (nl * TSTR + cob) * 2 + 4) = pk2[1];
        }
    }
    __syncthreads();
    for (int i = tid; i < 128 * 16; i += 512) {
        int nl = i >> 4, c8 = (i & 15) * 8;
        uint4 v = *(const uint4*)(lds + (nl * TSTR + c8) * 2);
        *(uint4*)(out + (n0 + nl) * 128 + c8) = v;
    }
}

// ---------------------------------------------------------------------------
// MFMA implicit-GEMM fused LRnet conv. NHWC fp16 input. 512 thr.
// Wave split MW x (8/MW) (template). T14 async-stage kept.
// HASBN=1: apply relu(x*bnsc[c]+bnsh[c]) during stage (padding stays 0).
// MODE 0/1/3/4 as before.
// ---------------------------------------------------------------------------
template<int Ci, int Hin, int Win, int Co, int Hout, int Wout, int STRIDE,
         int ROWS, int IPB, int NTILE, int CHUNK, int MTILE, int MW, int HASBN, int MODE>
__global__ __launch_bounds__(512) void conv_mfma(
    const unsigned short* __restrict__ in,
    const unsigned short* __restrict__ wpk,
    const float* __restrict__ bias,
    const float* __restrict__ ones_g,
    const float* __restrict__ epsb,
    const float* __restrict__ bnsc,
    const float* __restrict__ bnsh,
    void* __restrict__ outp)
{
    constexpr int BLK = 512;
    constexpr int PROWS = STRIDE * (ROWS - 1) + 3;
    constexpr int PW = Win + 2;
    constexpr int POS = IPB * PROWS * PW;
    constexpr int NCH32 = Ci / 32;
    constexpr int NCHL = Ci / CHUNK;
    constexpr int KS = CHUNK / 32;
    constexpr int MFg = Co / 16;
    constexpr int NF = NTILE / 16;
    constexpr int NW = 8 / MW;
    constexpr int WMF = MTILE / (16 * MW);
    constexpr int WNF = NF / NW;
    constexpr int CT = Co / MTILE;
    constexpr int RG = Hout / ROWS;
    constexpr int LINE = CHUNK * 2 + 16;
    constexpr int TSTR = MTILE + 8;
    constexpr int PASSN = (NTILE < 128) ? NTILE : 128;
    constexpr int NPASS = (MODE == 4) ? 0 : NTILE / PASSN;
    constexpr int STAGE_B = POS * LINE;
    constexpr int TR_B = (MODE == 4) ? 0 : PASSN * TSTR * 2;
    constexpr int LDS_B = STAGE_B > TR_B ? STAGE_B : TR_B;
    constexpr int NV = POS * (CHUNK / 8);
    constexpr int NLD = (NV + BLK - 1) / BLK;
    static_assert(8 % CT == 0, "ct swizzle");
    static_assert(WNF * NW == NF, "wnf");
    static_assert(WMF * 16 * MW == MTILE, "wmf");
    static_assert(NCHL * CHUNK == Ci, "chunk");
    static_assert(LDS_B <= 65536, "lds");
    __shared__ char lds[LDS_B];

    const int tid = threadIdx.x;
    const int lane = tid & 63;
    const int wv = tid >> 6;
    const int wm = wv % MW, wn = wv / MW;
    const int g = lane >> 4, ln = lane & 15;

    const int bid = blockIdx.x;
    const int xcd = bid & 7;
    constexpr int XPC = 8 / CT;
    const int ct = xcd % CT;
    const int nt = (bid >> 3) * XPC + xcd / CT;
    const int b0 = (nt / RG) * IPB;
    const int y0 = (nt % RG) * ROWS;

    int pbase[WNF];
#pragma unroll
    for (int nf = 0; nf < WNF; nf++) {
        int n = (wn * WNF + nf) * 16 + ln;
        int img = n / (ROWS * Wout);
        int rem = n % (ROWS * Wout);
        int yr = rem / Wout, xo = rem % Wout;
        pbase[nf] = (img * PROWS + STRIDE * yr) * PW + STRIDE * xo;
    }

    // ---- precompute per-thread stage addresses (ch-invariant) ----
    const unsigned short* gsrc[NLD];
    int ldst[NLD];
    int cseg[NLD];
#pragma unroll
    for (int j = 0; j < NLD; j++) {
        int i = tid + j * BLK;
        gsrc[j] = nullptr; ldst[j] = 0; cseg[j] = 0;
        if (i < NV) {
            int p = i / (CHUNK / 8), c = i % (CHUNK / 8);
            int img = p / (PROWS * PW);
            int r = p % (PROWS * PW);
            int prow = r / PW, px = r % PW;
            int yin = STRIDE * y0 - 1 + prow;
            int xin = px - 1;
            ldst[j] = p * LINE + c * 16;
            cseg[j] = c * 8;
            if (yin >= 0 && yin < Hin && xin >= 0 && xin < Win)
                gsrc[j] = in + (((long)(b0 + img) * Hin + yin) * Win + xin) * Ci + c * 8;
        }
    }

    f32x4 accA[WMF][WNF], accB[WMF][WNF];
#pragma unroll
    for (int mf = 0; mf < WMF; mf++)
#pragma unroll
    for (int nf = 0; nf < WNF; nf++) {
        accA[mf][nf] = (f32x4){0.f, 0.f, 0.f, 0.f};
        accB[mf][nf] = (f32x4){0.f, 0.f, 0.f, 0.f};
    }

    const unsigned short* wbase = wpk + ((long)(ct * (MTILE / 16) + wm * WMF) * 64 + lane) * 8;

    // issue chunk-0 loads
    uint4 regs[NLD];
#pragma unroll
    for (int j = 0; j < NLD; j++) {
        uint4 v; v.x = 0; v.y = 0; v.z = 0; v.w = 0;
        if (tid + j * BLK < NV && gsrc[j]) v = *(const uint4*)(gsrc[j]);
        regs[j] = v;
    }

    for (int ch = 0; ch < NCHL; ch++) {
        // ---- write chunk ch (BN fused if HASBN; padding stays zero) ----
#pragma unroll
        for (int j = 0; j < NLD; j++)
            if (tid + j * BLK < NV) {
                uint4 v = regs[j];
                if constexpr (HASBN) {
                    if (gsrc[j]) {
                        int cb = ch * CHUNK + cseg[j];
                        unsigned int* vp = (unsigned int*)&v;
#pragma unroll
                        for (int e = 0; e < 4; e++) {
                            float lo = h2f((unsigned short)(vp[e] & 0xffffu));
                            float hi = h2f((unsigned short)(vp[e] >> 16));
                            lo = fmaf(lo, bnsc[cb + 2 * e], bnsh[cb + 2 * e]);
                            lo = lo > 0.f ? lo : 0.f;
                            hi = fmaf(hi, bnsc[cb + 2 * e + 1], bnsh[cb + 2 * e + 1]);
                            hi = hi > 0.f ? hi : 0.f;
                            vp[e] = (unsigned int)f2h(lo) | (((unsigned int)f2h(hi)) << 16);
                        }
                    }
                }
                *(uint4*)(lds + ldst[j]) = v;
            }
        __syncthreads();
        // ---- issue chunk ch+1 loads ----
        if (ch + 1 < NCHL) {
#pragma unroll
            for (int j = 0; j < NLD; j++) {
                uint4 v; v.x = 0; v.y = 0; v.z = 0; v.w = 0;
                if (tid + j * BLK < NV && gsrc[j])
                    v = *(const uint4*)(gsrc[j] + (long)(ch + 1) * CHUNK);
                regs[j] = v;
            }
        }
        // ---- compute chunk ch ----
#pragma unroll 3
        for (int pos = 0; pos < 9; pos++) {
            const int ky = pos / 3, kx = pos % 3;
#pragma unroll
            for (int ks = 0; ks < KS; ks++) {
                const int ch32 = ch * KS + ks;
                half8 af[2][WMF];
#pragma unroll
                for (int cv = 0; cv < 2; cv++)
#pragma unroll
                for (int mf = 0; mf < WMF; mf++)
                    af[cv][mf] = *(const half8*)(wbase +
                        ((long)(((cv * 9 + pos) * NCH32 + ch32) * MFg + mf)) * 512);
#pragma unroll
                for (int nf = 0; nf < WNF; nf++) {
                    int po = (pbase[nf] + ky * PW + kx) * LINE + ks * 64 + g * 16;
                    half8 b1 = *(const half8*)(lds + po);
                    half8 b2 = b1 * b1;               // v_pk_mul_f16
#pragma unroll
                    for (int mf = 0; mf < WMF; mf++) {
                        accA[mf][nf] = __builtin_amdgcn_mfma_f32_16x16x32_f16(af[0][mf], b1, accA[mf][nf], 0, 0, 0);
                        accB[mf][nf] = __builtin_amdgcn_mfma_f32_16x16x32_f16(af[1][mf], b2, accB[mf][nf], 0, 0, 0);
                    }
                }
            }
        }
        __syncthreads();
    }

    // ---- epilogue ----
    if constexpr (MODE == 4) {
        unsigned short* out = (unsigned short*)outp;
#pragma unroll
        for (int mf = 0; mf < WMF; mf++) {
            int co = ct * MTILE + (wm * WMF + mf) * 16 + g * 4;
#pragma unroll
            for (int nf = 0; nf < WNF; nf++) {
                int n = (wn * WNF + nf) * 16 + ln;
                int img = n / (ROWS * Wout), rem = n % (ROWS * Wout);
                int y = y0 + rem / Wout, x = rem % Wout;
                int b = b0 + img;
#pragma unroll
                for (int r = 0; r < 4; r++) {
                    int c = co + r;
                    float m = accA[mf][nf][r] + bias[c];
                    float v = ones_g[(c * Hout + y) * Wout + x] - accB[mf][nf][r];
                    long oi = (((long)b * Co + c) * Hout + y) * Wout + x;
                    out[oi] = f2h(m + sqrtf(v + EPSV) * epsb[oi]);
                }
            }
        }
    } else {
        unsigned short* out = (unsigned short*)outp;
#pragma unroll
        for (int pass = 0; pass < NPASS; pass++) {
            __syncthreads();
#pragma unroll
            for (int mf = 0; mf < WMF; mf++) {
                int cob = (wm * WMF + mf) * 16 + g * 4;
                int cg = ct * MTILE + cob;
#pragma unroll
                for (int nf = 0; nf < WNF; nf++) {
                    int nb = (wn * WNF + nf) * 16;
                    if (nb < pass * PASSN || nb >= (pass + 1) * PASSN) continue;
                    int n = nb + ln;
                    int img = n / (ROWS * Wout), rem = n % (ROWS * Wout);
                    int y = y0 + rem / Wout, x = rem % Wout;
                    int b = b0 + img;
                    unsigned int pk2[2];
#pragma unroll
                    for (int r = 0; r < 4; r++) {
                        int c = cg + r;
                        float m = accA[mf][nf][r] + bias[c];
                        float val;
                        if constexpr (MODE == 0) {
                            val = erff(m * rsqrtf(accB[mf][nf][r] + EPSV) * INV_SQRT2);
                        } else if constexpr (MODE == 1) {
                            float v = ones_g[(c * Hout + y) * Wout + x] - accB[mf][nf][r];
                            val = erff(m * rsqrtf(v + EPSV) * INV_SQRT2);
                        } else { // MODE 3
                            float v = ones_g[(c * Hout + y) * Wout + x] - accB[mf][nf][r];
                            float ev = epsb[(((long)b * Co + c) * Hout + y) * Wout + x];
                            val = m + sqrtf(v + EPSV) * ev;
                        }
                        unsigned int hv = f2h(val);
                        if (r & 1) pk2[r >> 1] |= hv << 16; else pk2[r >> 1] = hv;
                    }
                    int nl = n - pass * PASSN;
                    *(unsigned int*)(lds + (nl * TSTR + cob) * 2) = pk2[0];
                    *(unsigned int*)(lds + (nl * TSTR + cob) * 2 + 4) = pk2[1];
                }
            }
            __syncthreads();
            for (int i = tid; i < PASSN * (MTILE / 8); i += BLK) {
                int nl = i / (MTILE / 8);
                int n = pass * PASSN + nl;
                int c8 = (i % (MTILE / 8)) * 8;
                int img = n / (ROWS * Wout), rem = n % (ROWS * Wout);
                int y = y0 + rem / Wout, x = rem % Wout;
                int b = b0 + img;
                uint4 val = *(const uint4*)(lds + (nl * TSTR + c8) * 2);
                long oa = (((long)b * Hout + y) * Wout + x) * Co + ct * MTILE + c8;
                *(uint4*)(out + oa) = val;
            }
        }
    }
}

// ---------------------------------------------------------------------------
// BatchNorm stats (fp16 activations, partial-sum based, no atomics)
// ---------------------------------------------------------------------------
__global__ void bn_part_nhwc(const unsigned short* __restrict__ h, float* __restrict__ part,
                             int C, int rpc) {
    int c = threadIdx.x;
    long r0 = (long)blockIdx.x * rpc;
    float s = 0.f, s2 = 0.f;
    for (int r = 0; r < rpc; r++) {
        float v = h2f(h[(r0 + r) * C + c]);
        s += v; s2 += v * v;
    }
    part[(long)blockIdx.x * 2 * C + c] = s;
    part[(long)blockIdx.x * 2 * C + C + c] = s2;
}

__global__ void bn_part_nchw(const unsigned short* __restrict__ h, float* __restrict__ part,
                             int ipc) {
    int c = threadIdx.x;
    int b0 = blockIdx.x * ipc;
    float s = 0.f, s2 = 0.f;
    for (int b = 0; b < ipc; b++) {
        const unsigned short* p = h + ((long)(b0 + b) * 512 + c) * 16;
        uint4 v0 = *(const uint4*)p;
        uint4 v1 = *(const uint4*)(p + 8);
        unsigned int* vp0 = (unsigned int*)&v0;
        unsigned int* vp1 = (unsigned int*)&v1;
#pragma unroll
        for (int e = 0; e < 4; e++) {
            float a = h2f((unsigned short)(vp0[e] & 0xffffu)), bb = h2f((unsigned short)(vp0[e] >> 16));
            float cc = h2f((unsigned short)(vp1[e] & 0xffffu)), d = h2f((unsigned short)(vp1[e] >> 16));
            s += a + bb + cc + d;
            s2 += a * a + bb * bb + cc * cc + d * d;
        }
    }
    part[(long)blockIdx.x * 1024 + c] = s;
    part[(long)blockIdx.x * 1024 + 512 + c] = s2;
}

__global__ void bn_fin(const float* __restrict__ part, const float* __restrict__ gamma,
                       const float* __restrict__ beta, float* __restrict__ sc,
                       float* __restrict__ sh, int C, int chunks, float invN) {
    int c = blockIdx.x * 256 + threadIdx.x;
    if (c >= C) return;
    float s = 0.f, s2 = 0.f;
    for (int j = 0; j < chunks; j++) {
        s += part[(long)j * 2 * C + c];
        s2 += part[(long)j * 2 * C + C + c];
    }
    float mean = s * invN;
    float var = s2 * invN - mean * mean;
    float k = gamma[c] * rsqrtf(var + BNEPS);
    sc[c] = k;
    sh[c] = beta[c] - mean * k;
}

// ---------------------------------------------------------------------------
// FC1 fp16 MFMA split-K. BN6 (sc/sh + relu) fused into A-stage.
// ---------------------------------------------------------------------------
__global__ __launch_bounds__(256) void fc1_mfma(const unsigned short* __restrict__ Ab,
                                                const unsigned short* __restrict__ Wp,
                                                const float* __restrict__ sc6,
                                                const float* __restrict__ sh6,
                                                float* __restrict__ pbuf) {
    __shared__ char lds[2 * 64 * 80];
    const int tid = threadIdx.x;
    const int lane = tid & 63;
    const int wv = tid >> 6;
    const int g = lane >> 4, ln = lane & 15;
    const int ot = blockIdx.x, bt = blockIdx.y, s = blockIdx.z;
    const int b0 = bt * 64;
    const int k0g = s * 1024;

    f32x4 acc[2][4];
#pragma unroll
    for (int c = 0; c < 2; c++)
#pragma unroll
    for (int nf = 0; nf < 4; nf++) acc[c][nf] = (f32x4){0.f, 0.f, 0.f, 0.f};

    for (int k0 = 0; k0 < 1024; k0 += 64) {
        __syncthreads();
        for (int i = tid; i < 512; i += 256) {
            int row = i >> 3, kk = (i >> 2) & 1, seg = i & 3;
            int kidx = k0g + k0 + kk * 32 + seg * 8;
            uint4 v = *(const uint4*)(Ab + ((long)(b0 + row) * 8192 + kidx));
            // fused BN6 + relu (one channel per 8-half load)
            int c = kidx >> 4;
            float kc = sc6[c], tc = sh6[c];
            unsigned int* vp = (unsigned int*)&v;
#pragma unroll
            for (int e = 0; e < 4; e++) {
                float lo = h2f((unsigned short)(vp[e] & 0xffffu));
                float hi = h2f((unsigned short)(vp[e] >> 16));
                lo = fmaf(lo, kc, tc); lo = lo > 0.f ? lo : 0.f;
                hi = fmaf(hi, kc, tc); hi = hi > 0.f ? hi : 0.f;
                vp[e] = (unsigned int)f2h(lo) | (((unsigned int)f2h(hi)) << 16);
            }
            *(uint4*)(lds + (kk * 64 + row) * 80 + seg * 16) = v;
        }
        __syncthreads();
#pragma unroll
        for (int kk = 0; kk < 2; kk++) {
            int kt = (k0g + k0) / 32 + kk;
            half8 af[2];
#pragma unroll
            for (int c = 0; c < 2; c++) {
                int mf = ot * 8 + wv * 2 + c;
                af[c] = *(const half8*)(Wp + (((long)kt * 64 + mf) * 64 + lane) * 8);
            }
            half8 bf[4];
#pragma unroll
            for (int nf = 0; nf < 4; nf++)
                bf[nf] = *(const half8*)(lds + (kk * 64 + nf * 16 + ln) * 80 + g * 16);
#pragma unroll
            for (int c = 0; c < 2; c++)
#pragma unroll
            for (int nf = 0; nf < 4; nf++)
                acc[c][nf] = __builtin_amdgcn_mfma_f32_16x16x32_f16(af[c], bf[nf], acc[c][nf], 0, 0, 0);
        }
    }
#pragma unroll
    for (int c = 0; c < 2; c++) {
        int o = ot * 128 + (wv * 2 + c) * 16 + g * 4;
#pragma unroll
        for (int nf = 0; nf < 4; nf++) {
            int b = b0 + nf * 16 + ln;
            *(f32x4*)(pbuf + ((long)s * 256 + b) * 1024 + o) = acc[c][nf];
        }
    }
}

// FC2 with fused fc1 split-K reduction + bias + relu (bit-identical to old chain)
__global__ void fc2_k(const float* __restrict__ pbuf, const float* __restrict__ fc1b,
                      const float* __restrict__ W, const float* __restrict__ b2,
                      float* __restrict__ out) {
    int bb = blockIdx.x;
    int tid = threadIdx.x;
    float acc[10];
#pragma unroll
    for (int o = 0; o < 10; o++) acc[o] = 0.f;
    for (int k = tid; k < 1024; k += 256) {
        float s = 0.f;
#pragma unroll
        for (int j = 0; j < 8; j++) s += pbuf[(long)j * 262144 + bb * 1024 + k];
        s += fc1b[k];
        float a = s > 0.f ? s : 0.f;
#pragma unroll
        for (int o = 0; o < 10; o++) acc[o] = fmaf(a, W[o * 1024 + k], acc[o]);
    }
#pragma unroll
    for (int o = 0; o < 10; o++)
        for (int off = 32; off > 0; off >>= 1) acc[o] += __shfl_down(acc[o], off);
    __shared__ float red[10][4];
    int wid = tid >> 6, lane = tid & 63;
    if (lane == 0) {
#pragma unroll
        for (int o = 0; o < 10; o++) red[o][wid] = acc[o];
    }
    __syncthreads();
    if (tid < 10)
        out[bb * 10 + tid] = red[tid][0] + red[tid][1] + red[tid][2] + red[tid][3] + b2[tid];
}

// ---------------------------------------------------------------------------
extern "C" void kernel_launch(void* const* d_in, const int* in_sizes, int n_in,
                              void* d_out, int out_size, void* d_ws, size_t ws_size,
                              hipStream_t stream) {
    const float* x  = (const float*)d_in[0];
    const float* a1 = (const float*)d_in[1];  const float* b1 = (const float*)d_in[2];  const float* c1 = (const float*)d_in[3];
    const float* a2 = (const float*)d_in[4];  const float* b2 = (const float*)d_in[5];  const float* c2 = (const float*)d_in[6];
    const float* a3 = (const float*)d_in[7];  const float* b3 = (const float*)d_in[8];  const float* c3 = (const float*)d_in[9];
    const float* a4 = (const float*)d_in[10]; const float* b4 = (const float*)d_in[11]; const float* c4 = (const float*)d_in[12];
    const float* a5 = (const float*)d_in[13]; const float* b5 = (const float*)d_in[14]; const float* c5 = (const float*)d_in[15];
    const float* a6 = (const float*)d_in[16]; const float* b6 = (const float*)d_in[17]; const float* c6 = (const float*)d_in[18];
    const float* g3 = (const float*)d_in[19]; const float* be3 = (const float*)d_in[20];
    const float* g6 = (const float*)d_in[21]; const float* be6 = (const float*)d_in[22];
    const float* fc1w = (const float*)d_in[23]; const float* fc1b = (const float*)d_in[24];
    const float* fc2w = (const float*)d_in[25]; const float* fc2b = (const float*)d_in[26];
    const float* eps3 = (const float*)d_in[27]; const float* eps6 = (const float*)d_in[28];
    (void)in_sizes; (void)n_in; (void)out_size; (void)ws_size;

    float* w = (float*)d_ws;
    size_t off = 0;
    auto alloc = [&](size_t n) { float* p = w + off; off += n; return p; };
    unsigned short* pk2 = (unsigned short*)alloc(147456);
    unsigned short* pk3 = (unsigned short*)alloc(294912);
    unsigned short* pk4 = (unsigned short*)alloc(589824);
    unsigned short* pk5 = (unsigned short*)alloc(1179648);
    unsigned short* pk6 = (unsigned short*)alloc(2359296);
    unsigned short* pkL1 = (unsigned short*)alloc(4096);
    float* ss2 = alloc(1152); float* ss3 = alloc(2304);
    float* ss5 = alloc(4608); float* ss6 = alloc(4608);
    float* og2 = alloc(32768); float* og3 = alloc(65536);
    float* og5 = alloc(32768); float* og6 = alloc(8192);
    float* part3 = alloc(131072);
    float* part6 = alloc(65536);
    float* sc3 = alloc(256); float* sh3 = alloc(256);
    float* sc6 = alloc(512); float* sh6 = alloc(512);
    float* A  = alloc(16777216);
    float* Bb = alloc(4194304);
    float* Cc = alloc(8388608);
    float* Dd = alloc(2097152);
    float* Ee = alloc(4194304);

    unsigned short* ex1 = (unsigned short*)A;
    unsigned short* pkF = (unsigned short*)A;
    float*          pbuf = A + 4194304;
    unsigned short* ex2 = (unsigned short*)Bb;
    unsigned short* h6b = (unsigned short*)(Bb + 524288);
    unsigned short* h3b = (unsigned short*)Cc;
    unsigned short* ex4 = (unsigned short*)Dd;
    unsigned short* ex5 = (unsigned short*)Ee;

    // ---- prep (fused) ----
    prep_all<<<2588, 256, 0, stream>>>(a1, b1, pkL1, a2, b2, pk2, a3, b3, pk3,
                                       a4, b4, pk4, a5, b5, pk5, a6, b6, pk6,
                                       ss2, ss3, ss5, ss6);
    prep_ones_all<<<544, 256, 0, stream>>>(ss2, ss3, ss5, ss6, og2, og3, og5, og6);

    // ---- network ----
    // L1: fused im2col + MFMA GEMM -> ex1 [256,32,32,128] NHWC fp16
    conv1_mfma<<<2048, 512, 0, stream>>>(x, pkL1, c1, ex1);
    // L2  (MW=4, MTILE=128, N-split: ROWS=4 -> NTILE=64, grid 1024)
    conv_mfma<128,32,32,128,16,16,2, 4,1,64,32,128,4,0,1><<<1024, 512, 0, stream>>>(ex1, pk2, c2, og2, nullptr, nullptr, nullptr, ex2);
    // L3  (MW=4, MTILE=128, NTILE=128, CHUNK=128 -> single K-chunk, grid 1024)
    conv_mfma<128,16,16,256,16,16,1, 8,1,128,128,128,4,0,3><<<1024, 512, 0, stream>>>(ex2, pk3, c3, og3, eps3, nullptr, nullptr, h3b);
    prep_fc1<<<4096, 256, 0, stream>>>(fc1w, pkF);
    // BN3 stats (pre-activation, matches reference)
    bn_part_nhwc<<<256, 256, 0, stream>>>(h3b, part3, 256, 256);
    bn_fin<<<1, 256, 0, stream>>>(part3, g3, be3, sc3, sh3, 256, 256, 1.f / 65536.f);
    // L4  (MW=4, MTILE=128, BN3 fused into stage)
    conv_mfma<256,16,16,256, 8, 8,2, 8,1,64,32,128,4,1,0><<<512, 512, 0, stream>>>(h3b, pk4, c4, nullptr, nullptr, sc3, sh3, ex4);
    // L5  (MW=4, MTILE=64, grid 1024)
    conv_mfma<256, 8, 8,512, 8, 8,1, 8,2,128,32,64,4,0,1><<<1024, 512, 0, stream>>>(ex4, pk5, c5, og5, nullptr, nullptr, nullptr, ex5);
    // L6  (MW=4, MTILE=64)
    conv_mfma<512, 8, 8,512, 4, 4,2, 4,4,64,32,64,4,0,4><<<512, 512, 0, stream>>>(ex5, pk6, c6, og6, eps6, nullptr, nullptr, h6b);
    // BN6 stats
    bn_part_nchw<<<64, 512, 0, stream>>>(h6b, part6, 4);
    bn_fin<<<2, 256, 0, stream>>>(part6, g6, be6, sc6, sh6, 512, 64, 1.f / 4096.f);
    // FC1 (BN6 fused into A-stage) + FC2 (fc1 reduction fused)
    fc1_mfma<<<dim3(8, 4, 8), 256, 0, stream>>>(h6b, pkF, sc6, sh6, pbuf);
    fc2_k<<<256, 256, 0, stream>>>(pbuf, fc1b, fc2w, fc2b, (float*)d_out);
}